// Round 1
// baseline (359.151 us; speedup 1.0000x reference)
//
#include <hip/hip_runtime.h>
#include <math.h>

// UpPolyAct: out = c0 + c1*x + c2*Q(x)
// Q = 0.25*(z_ee + z_eo*M + M^T*(z_oe + z_oo*M))
//   z_ee = (E X E)^2, z_eo = (E X M^T)^2, z_oe = (M X E)^2, z_oo = (M X M^T)^2
//   E = I + s s^T/64 (s_t = (-1)^t),  M[t][m] = g[(t-m) mod 64],
//   g[e] = (1/64)(1 + 2*sum_{k=1..32} cos(pi*k*(2e+1)/64))
// Derivation: B(upsample->poly->lpf->decimate) has linear part == identity;
// only the quadratic term needs the polyphase filter matmuls (6 x 64^3/chan).

#define LS 66  // padded LDS row stride (even for 8B align, breaks 32-bank stride)

template <int MODE, bool ACC>
__device__ __forceinline__ void matmul_g(float* __restrict__ C,
                                         const float* __restrict__ A,
                                         const float* __restrict__ g2, int tid) {
  // MODE 0: C = M   * A   : C[i][j] = sum_m g[(i-m)&63] * A[m][j]
  // MODE 1: C = A   * M^T : C[i][j] = sum_m A[i][m] * g[(j-m)&63]
  // MODE 2: C = A   * M   : C[i][j] = sum_m A[i][m] * g[(m-j)&63]
  // MODE 3: C = M^T * A   : C[i][j] = sum_m g[(m-i)&63] * A[m][j]
  const int ty = tid >> 4, tx = tid & 15;
  const int i0 = ty << 2, j0 = tx << 2;
  float acc[4][4];
#pragma unroll
  for (int r = 0; r < 4; ++r)
#pragma unroll
    for (int c = 0; c < 4; ++c) acc[r][c] = 0.0f;

  for (int m = 0; m < 64; ++m) {
    float av[4], bv[4];
    if (MODE == 0) {
#pragma unroll
      for (int r = 0; r < 4; ++r) av[r] = g2[64 + i0 + r - m];
#pragma unroll
      for (int c = 0; c < 4; ++c) bv[c] = A[m * LS + j0 + c];
    } else if (MODE == 1) {
#pragma unroll
      for (int r = 0; r < 4; ++r) av[r] = A[(i0 + r) * LS + m];
#pragma unroll
      for (int c = 0; c < 4; ++c) bv[c] = g2[64 + j0 + c - m];
    } else if (MODE == 2) {
#pragma unroll
      for (int r = 0; r < 4; ++r) av[r] = A[(i0 + r) * LS + m];
#pragma unroll
      for (int c = 0; c < 4; ++c) bv[c] = g2[64 + m - j0 - c];
    } else {
#pragma unroll
      for (int r = 0; r < 4; ++r) av[r] = g2[64 + m - i0 - r];
#pragma unroll
      for (int c = 0; c < 4; ++c) bv[c] = A[m * LS + j0 + c];
    }
#pragma unroll
    for (int r = 0; r < 4; ++r)
#pragma unroll
      for (int c = 0; c < 4; ++c) acc[r][c] += av[r] * bv[c];
  }
#pragma unroll
  for (int r = 0; r < 4; ++r)
#pragma unroll
    for (int c = 0; c < 4; ++c) {
      const int idx = (i0 + r) * LS + j0 + c;
      if (ACC)
        C[idx] += acc[r][c];
      else
        C[idx] = acc[r][c];
    }
}

__global__ __launch_bounds__(256, 2) void uppolyact_kernel(
    const float* __restrict__ x, const float* __restrict__ coef,
    float* __restrict__ out) {
  __shared__ float g2[128];
  __shared__ float Xs[64 * LS];
  __shared__ float A1[64 * LS];
  __shared__ float A2[64 * LS];
  __shared__ float A3[64 * LS];
  __shared__ float redA[64];
  __shared__ float redB[64];
  __shared__ float sig;

  const int tid = threadIdx.x;
  const size_t base = (size_t)blockIdx.x * 4096;

  // Build duplicated circulant table g2[e] = g[e & 63], e in [0,128).
  if (tid < 128) {
    const int d = 2 * (tid & 63) + 1;
    float s = 1.0f;
    for (int k = 1; k <= 32; ++k) {
      const int q = (k * d) & 127;  // cos(pi*q/64), arg kept tiny for accuracy
      s += 2.0f * cosf((float)M_PI * (1.0f / 64.0f) * (float)q);
    }
    g2[tid] = s * (1.0f / 64.0f);
  }
  // Load X (coalesced float4) into padded LDS.
  {
    const float4* xv = (const float4*)(x + base);
    for (int k = tid; k < 1024; k += 256) {
      const float4 v = xv[k];
      const int r = k >> 4, c = (k & 15) << 2;
      float* p = &Xs[r * LS + c];
      p[0] = v.x; p[1] = v.y; p[2] = v.z; p[3] = v.w;
    }
  }
  __syncthreads();

  matmul_g<0, false>(A1, Xs, g2, tid);  // L = M X
  matmul_g<1, false>(A2, Xs, g2, tid);  // R = X M^T
  __syncthreads();
  matmul_g<0, false>(A3, A2, g2, tid);  // xu_oo = M R
  __syncthreads();

  // redA[j] = sum_m sgn(m) R[m][j]  (col sums), redB[i] = sum_m sgn(m) L[i][m]
  if (tid < 64) {
    float sa = 0.0f, sb = 0.0f;
    for (int m = 0; m < 64; ++m) {
      const float sg = (m & 1) ? -1.0f : 1.0f;
      sa += sg * A2[m * LS + tid];
      sb += sg * A1[tid * LS + m];
    }
    redA[tid] = sa;
    redB[tid] = sb;
  }
  __syncthreads();

  // Apply rank-1 E corrections, then square: z_eo, z_oe, z_oo.
  for (int k = tid; k < 4096; k += 256) {
    const int i = k >> 6, j = k & 63;
    const int idx = i * LS + j;
    const float sgi = (i & 1) ? -1.0f : 1.0f;
    const float sgj = (j & 1) ? -1.0f : 1.0f;
    const float veo = A2[idx] + (1.0f / 64.0f) * sgi * redA[j];
    A2[idx] = veo * veo;
    const float voe = A1[idx] + (1.0f / 64.0f) * sgj * redB[i];
    A1[idx] = voe * voe;
    const float voo = A3[idx];
    A3[idx] = voo * voo;
  }
  __syncthreads();

  // z_ee = (E X E)^2: needs signed col sums, row sums, and total of X.
  if (tid < 64) {
    float sa = 0.0f, sb = 0.0f;
    for (int m = 0; m < 64; ++m) {
      const float sg = (m & 1) ? -1.0f : 1.0f;
      sa += sg * Xs[m * LS + tid];
      sb += sg * Xs[tid * LS + m];
    }
    redA[tid] = sa;
    redB[tid] = sb;
  }
  __syncthreads();
  if (tid == 0) {
    float s = 0.0f;
    for (int j = 0; j < 64; ++j) s += ((j & 1) ? -1.0f : 1.0f) * redA[j];
    sig = s;
  }
  __syncthreads();
  for (int k = tid; k < 4096; k += 256) {
    const int i = k >> 6, j = k & 63;
    const int idx = i * LS + j;
    const float sgi = (i & 1) ? -1.0f : 1.0f;
    const float sgj = (j & 1) ? -1.0f : 1.0f;
    const float v = Xs[idx] + (1.0f / 64.0f) * (sgi * redA[j] + sgj * redB[i]) +
                    (1.0f / 4096.0f) * sgi * sgj * sig;
    Xs[idx] = v * v;
  }
  __syncthreads();

  matmul_g<2, true>(A1, A3, g2, tid);   // u = z_oe + z_oo*M   (A1 += A3*M)
  __syncthreads();
  matmul_g<3, false>(A3, A1, g2, tid);  // v = M^T u
  __syncthreads();
  matmul_g<2, false>(A1, A2, g2, tid);  // w = z_eo*M
  __syncthreads();

  // out = c0 + c1*x + 0.25*c2*(z_ee + v + w)
  const float c0 = coef[0], c1 = coef[1], c2 = coef[2];
  const float4* xv = (const float4*)(x + base);
  float4* ov = (float4*)(out + base);
  for (int k = tid; k < 1024; k += 256) {
    const float4 xin = xv[k];
    const int r = k >> 4, c = (k & 15) << 2;
    const int idx = r * LS + c;
    float4 o;
    o.x = c0 + c1 * xin.x + 0.25f * c2 * (Xs[idx + 0] + A3[idx + 0] + A1[idx + 0]);
    o.y = c0 + c1 * xin.y + 0.25f * c2 * (Xs[idx + 1] + A3[idx + 1] + A1[idx + 1]);
    o.z = c0 + c1 * xin.z + 0.25f * c2 * (Xs[idx + 2] + A3[idx + 2] + A1[idx + 2]);
    o.w = c0 + c1 * xin.w + 0.25f * c2 * (Xs[idx + 3] + A3[idx + 3] + A1[idx + 3]);
    ov[k] = o;
  }
}

extern "C" void kernel_launch(void* const* d_in, const int* in_sizes, int n_in,
                              void* d_out, int out_size, void* d_ws,
                              size_t ws_size, hipStream_t stream) {
  const float* x = (const float*)d_in[0];
  const float* coef = (const float*)d_in[1];
  float* out = (float*)d_out;
  const int channels = out_size / 4096;  // 32*128 = 4096 channels of 64x64
  uppolyact_kernel<<<dim3(channels), dim3(256), 0, stream>>>(x, coef, out);
}

// Round 2
// 149.685 us; speedup vs baseline: 2.3994x; 2.3994x over previous
//
#include <hip/hip_runtime.h>
#include <math.h>

// UpPolyAct: out = c0 + c1*x + 0.25*c2*( z_ee + V + W )
//   R = X M^T, L = M X, OO = L M^T
//   z_eo=(R+corr)^2, z_oe=(L+corr)^2, z_oo=OO^2, z_ee=(E X E)^2
//   U = z_oe + z_oo M,  V = M^T U,  W = z_eo M
// MFMA plan (32x32x16 bf16, 1 tile/wave, T-domain through U):
//   Rt = M X^T        A=tab(gr,rb)  B=Xr rows
//   Lt = X^T M^T      A=Xc rows     B=tab(gr,cb)
//   OOt = M Lt        A=tab(gr,rb)  B=Lr rows      (Lr = L row-major, T-write)
//   Ut = zoeT + M^T zooT   A=tab(g,rb)  B=Zoo rows (acc init = z_oeT regs)
//   W  = z_eo M       A=Zeo rows    B=tab(g,cb)    (untransposed)
//   V  = M^T U        A=tab(g,rb)   B=UtR rows     (untransposed)

typedef short short8 __attribute__((ext_vector_type(8)));
typedef float f32x16 __attribute__((ext_vector_type(16)));

#define LSH 68  // bf16 LDS row stride (68 shorts = 136 B, rows 8B-aligned)

__device__ __forceinline__ short f2bf(float f) {
  unsigned u = __float_as_uint(f);
  u += 0x7FFFu + ((u >> 16) & 1u);
  return (short)(u >> 16);
}
__device__ __forceinline__ float bf2f(short s) {
  return __uint_as_float(((unsigned)(unsigned short)s) << 16);
}
__device__ __forceinline__ short8 ldrow(const short* p) {
  union { unsigned u[4]; short8 s; } v;
  const uint2 lo = *(const uint2*)p;
  const uint2 hi = *(const uint2*)(p + 4);
  v.u[0] = lo.x; v.u[1] = lo.y; v.u[2] = hi.x; v.u[3] = hi.y;
  return v.s;
}

__global__ __launch_bounds__(256, 3) void uppolyact_kernel(
    const float* __restrict__ x, const float* __restrict__ coef,
    float* __restrict__ out) {
  __shared__ __align__(16) short Xr[64 * LSH];    // X row-major bf16
  __shared__ __align__(16) short XcZ[64 * LSH];   // X^T row-major, then z_eo row-major
  __shared__ __align__(16) short LrU[64 * LSH];   // L row-major, then U^T row-major
  __shared__ __align__(16) short Zoo[64 * LSH];   // z_oo row-major
  __shared__ __align__(16) short ftab[16 * 64 * 8];  // M fragments, slot=(t*2+blk)*4+kk
  __shared__ float g64[64];
  __shared__ float tvec[64], uvec[64], sRv[64], Luv[64];
  __shared__ float sigv;

  const int tid = threadIdx.x;
  const int lane = tid & 63;
  const int w = tid >> 6;
  const int q = lane >> 5;
  const int l31 = lane & 31;
  const int rb = w >> 1, cb = w & 1;
  const size_t base = (size_t)blockIdx.x * 4096;

  // ---- P0: g table, load X -> Xr + Xc (bf16) ----
  if (tid < 64) {
    const int d = 2 * tid + 1;
    float s = 1.0f;
    for (int k = 1; k <= 32; ++k) {
      const int qq = (k * d) & 127;
      s += 2.0f * cosf((float)M_PI * (1.0f / 64.0f) * (float)qq);
    }
    g64[tid] = s * (1.0f / 64.0f);
  }
  {
    const float4* xv = (const float4*)(x + base);
#pragma unroll
    for (int e = 0; e < 4; ++e) {
      const int k4 = tid + 256 * e;  // 0..1023 float4s
      const float4 v = xv[k4];
      const int r = k4 >> 4, c = (k4 & 15) << 2;
      const short b0 = f2bf(v.x), b1 = f2bf(v.y), b2 = f2bf(v.z), b3 = f2bf(v.w);
      short* pr = &Xr[r * LSH + c];
      pr[0] = b0; pr[1] = b1; pr[2] = b2; pr[3] = b3;
      XcZ[(c + 0) * LSH + r] = b0;
      XcZ[(c + 1) * LSH + r] = b1;
      XcZ[(c + 2) * LSH + r] = b2;
      XcZ[(c + 3) * LSH + r] = b3;
    }
  }
  __syncthreads();  // B1

  // ---- P0b: build M fragment table; signed sums t,u ----
#pragma unroll
  for (int e = 0; e < 4; ++e) {
    const int entry = tid + 256 * e;  // 0..1023
    const int s_ = entry >> 6, ln = entry & 63;
    const int t_ = s_ >> 3, blk = (s_ >> 2) & 1, kk = s_ & 3;
    const int basei = kk * 16 + (ln >> 5) * 8 - (ln & 31) - 32 * blk;
    short* dst = &ftab[(s_ * 64 + ln) * 8];
#pragma unroll
    for (int j = 0; j < 8; ++j) {
      const int i0 = basei + j;
      const int idx = t_ ? ((-i0) & 63) : (i0 & 63);
      dst[j] = f2bf(g64[idx]);
    }
  }
  if (tid < 64) {
    float acc = 0.0f;
    for (int i = 0; i < 64; ++i) {
      const float xv_ = bf2f(XcZ[tid * LSH + i]);
      acc += (i & 1) ? -xv_ : xv_;
    }
    tvec[tid] = acc;  // t[j] = sum_i s_i X[i][j]
  } else if (tid < 128) {
    const int i = tid - 64;
    float acc = 0.0f;
    for (int j = 0; j < 64; ++j) {
      const float xv_ = bf2f(Xr[i * LSH + j]);
      acc += (j & 1) ? -xv_ : xv_;
    }
    uvec[i] = acc;  // u[i] = sum_j X[i][j] s_j
  }
  __syncthreads();  // B2

  // ---- P-A: small matvecs (waves 0-1) + MFMA Rt, Lt (all) ----
  if (tid < 64) {
    float acc = 0.0f;
    for (int m = 0; m < 64; ++m) acc += tvec[m] * g64[(tid - m) & 63];
    sRv[tid] = acc;  // (s^T R)[j]
  } else if (tid < 128) {
    const int i = tid - 64;
    float acc = 0.0f;
    for (int m = 0; m < 64; ++m) acc += g64[(i - m) & 63] * uvec[m];
    Luv[i] = acc;  // (L s)[i]
  } else if (tid == 128) {
    float acc = 0.0f;
    for (int i = 0; i < 64; ++i) acc += (i & 1) ? -uvec[i] : uvec[i];
    sigv = acc;  // s^T X s
  }

  f32x16 Rt, Lt;
#pragma unroll
  for (int r = 0; r < 16; ++r) { Rt[r] = 0.0f; Lt[r] = 0.0f; }
#pragma unroll
  for (int kk = 0; kk < 4; ++kk) {
    const short8 aR = *(const short8*)&ftab[(((2 + rb) * 4 + kk) * 64 + lane) * 8];  // (gr,rb)
    const short8 bR = ldrow(&Xr[(cb * 32 + l31) * LSH + kk * 16 + q * 8]);
    Rt = __builtin_amdgcn_mfma_f32_32x32x16_bf16(aR, bR, Rt, 0, 0, 0);
    const short8 aL = ldrow(&XcZ[(rb * 32 + l31) * LSH + kk * 16 + q * 8]);
    const short8 bL = *(const short8*)&ftab[(((2 + cb) * 4 + kk) * 64 + lane) * 8];  // (gr,cb)
    Lt = __builtin_amdgcn_mfma_f32_32x32x16_bf16(aL, bL, Lt, 0, 0, 0);
  }
  __syncthreads();  // B3 (Xc reads done; sRv/Luv/sig ready)

  // ---- P2: z_eoT -> Zeo (T-write), Lt -> Lr (T-write), z_oeT regs ----
  float zoe[16];
#pragma unroll
  for (int r = 0; r < 16; ++r) {
    const int jrow = rb * 32 + (r & 3) + 4 * q + 8 * (r >> 2);
    const int icol = cb * 32 + l31;
    const float sgi = (icol & 1) ? -1.0f : 1.0f;
    const float sgj = (jrow & 1) ? -1.0f : 1.0f;
    const float veo = Rt[r] + sgi * sRv[jrow] * (1.0f / 64.0f);
    XcZ[icol * LSH + jrow] = f2bf(veo * veo);   // z_eo[i][j]
    LrU[icol * LSH + jrow] = f2bf(Lt[r]);       // L[i][j]
    const float voe = Lt[r] + Luv[icol] * sgj * (1.0f / 64.0f);
    zoe[r] = voe * voe;                         // z_oeT[j][i] (C-layout)
  }
  __syncthreads();  // B4

  // ---- P3: OOt = M*Lt ; z_oo -> Zoo (T-write) ----
  f32x16 OOt;
#pragma unroll
  for (int r = 0; r < 16; ++r) OOt[r] = 0.0f;
#pragma unroll
  for (int kk = 0; kk < 4; ++kk) {
    const short8 a = *(const short8*)&ftab[(((2 + rb) * 4 + kk) * 64 + lane) * 8];  // (gr,rb)
    const short8 b = ldrow(&LrU[(cb * 32 + l31) * LSH + kk * 16 + q * 8]);
    OOt = __builtin_amdgcn_mfma_f32_32x32x16_bf16(a, b, OOt, 0, 0, 0);
  }
#pragma unroll
  for (int r = 0; r < 16; ++r) {
    const int jrow = rb * 32 + (r & 3) + 4 * q + 8 * (r >> 2);
    const int icol = cb * 32 + l31;
    Zoo[icol * LSH + jrow] = f2bf(OOt[r] * OOt[r]);  // z_oo[i][j]
  }
  __syncthreads();  // B5

  // ---- P4: Ut = z_oeT + M^T z_ooT ; W = z_eo*M ; Ut -> LrU direct ----
  f32x16 Ut, Wv;
#pragma unroll
  for (int r = 0; r < 16; ++r) { Ut[r] = zoe[r]; Wv[r] = 0.0f; }
#pragma unroll
  for (int kk = 0; kk < 4; ++kk) {
    const short8 aU = *(const short8*)&ftab[(((0 + rb) * 4 + kk) * 64 + lane) * 8];  // (g,rb)
    const short8 bU = ldrow(&Zoo[(cb * 32 + l31) * LSH + kk * 16 + q * 8]);
    Ut = __builtin_amdgcn_mfma_f32_32x32x16_bf16(aU, bU, Ut, 0, 0, 0);
    const short8 aW = ldrow(&XcZ[(rb * 32 + l31) * LSH + kk * 16 + q * 8]);  // z_eo rows
    const short8 bW = *(const short8*)&ftab[(((0 + cb) * 4 + kk) * 64 + lane) * 8];  // (g,cb)
    Wv = __builtin_amdgcn_mfma_f32_32x32x16_bf16(aW, bW, Wv, 0, 0, 0);
  }
#pragma unroll
  for (int r = 0; r < 16; ++r) {
    const int jrow = rb * 32 + (r & 3) + 4 * q + 8 * (r >> 2);
    const int icol = cb * 32 + l31;
    LrU[jrow * LSH + icol] = f2bf(Ut[r]);  // U^T row-major (rows=j)
  }
  __syncthreads();  // B6

  // ---- P5: V = M^T U ; epilogue ----
  f32x16 Vv;
#pragma unroll
  for (int r = 0; r < 16; ++r) Vv[r] = 0.0f;
#pragma unroll
  for (int kk = 0; kk < 4; ++kk) {
    const short8 a = *(const short8*)&ftab[(((0 + rb) * 4 + kk) * 64 + lane) * 8];  // (g,rb)
    const short8 b = ldrow(&LrU[(cb * 32 + l31) * LSH + kk * 16 + q * 8]);
    Vv = __builtin_amdgcn_mfma_f32_32x32x16_bf16(a, b, Vv, 0, 0, 0);
  }

  const float c0 = coef[0], c1 = coef[1];
  const float c2q = 0.25f * coef[2];
  const float* xb = x + base;
  float* ob = out + base;
#pragma unroll
  for (int r = 0; r < 16; ++r) {
    const int irow = rb * 32 + (r & 3) + 4 * q + 8 * (r >> 2);
    const int jcol = cb * 32 + l31;
    const float sgi = (irow & 1) ? -1.0f : 1.0f;
    const float sgj = (jcol & 1) ? -1.0f : 1.0f;
    const float xv_ = bf2f(Xr[irow * LSH + jcol]);
    const float vee = xv_ + (sgi * tvec[jcol] + uvec[irow] * sgj) * (1.0f / 64.0f) +
                      sgi * sgj * sigv * (1.0f / 4096.0f);
    const float zee = vee * vee;
    const float xg = xb[irow * 64 + jcol];
    ob[irow * 64 + jcol] = c0 + c1 * xg + c2q * (zee + Vv[r] + Wv[r]);
  }
}

extern "C" void kernel_launch(void* const* d_in, const int* in_sizes, int n_in,
                              void* d_out, int out_size, void* d_ws,
                              size_t ws_size, hipStream_t stream) {
  const float* x = (const float*)d_in[0];
  const float* coef = (const float*)d_in[1];
  float* out = (float*)d_out;
  const int channels = out_size / 4096;  // 32*128 channels of 64x64
  uppolyact_kernel<<<dim3(channels), dim3(256), 0, stream>>>(x, coef, out);
}